// Round 1
// baseline (229.406 us; speedup 1.0000x reference)
//
#include <hip/hip_runtime.h>
#include <math.h>

#define BLOCK 256
#define EPS 1e-6f

struct F3 { float x, y, z; };
struct F4 { float x, y, z, w; };

__device__ __forceinline__ F3 cross3(F3 a, F3 b) {
    return F3{a.y * b.z - a.z * b.y,
              a.z * b.x - a.x * b.z,
              a.x * b.y - a.y * b.x};
}

__device__ __forceinline__ F3 add3(F3 a, F3 b) { return F3{a.x + b.x, a.y + b.y, a.z + b.z}; }
__device__ __forceinline__ F3 neg3(F3 a) { return F3{-a.x, -a.y, -a.z}; }

// rotate v by quaternion q: t = 2*cross(u,v); v + w*t + cross(u,t)
__device__ __forceinline__ F3 qrot(F4 q, F3 v) {
    F3 u{q.x, q.y, q.z};
    F3 t = cross3(u, v);
    t.x *= 2.0f; t.y *= 2.0f; t.z *= 2.0f;
    F3 c = cross3(u, t);
    return F3{v.x + q.w * t.x + c.x,
              v.y + q.w * t.y + c.y,
              v.z + q.w * t.z + c.z};
}

__device__ __forceinline__ F4 qmul(F4 q, F4 r) {
    return F4{
        q.w * r.x + q.x * r.w + q.y * r.z - q.z * r.y,
        q.w * r.y - q.x * r.z + q.y * r.w + q.z * r.x,
        q.w * r.z + q.x * r.y - q.y * r.x + q.z * r.w,
        q.w * r.w - q.x * r.x - q.y * r.y - q.z * r.z};
}

__global__ void __launch_bounds__(BLOCK) pose_graph_kernel(
    const int* __restrict__ edges,   // [n,2] int32
    const float* __restrict__ poses, // [n,7]
    const float* __restrict__ nodes, // [N_NODES,7]
    float* __restrict__ out,         // [n,6]
    int n)
{
    __shared__ float sp[BLOCK * 7];
    __shared__ float so[BLOCK * 6];

    const int tid = threadIdx.x;
    const long long base = (long long)blockIdx.x * BLOCK;
    const int limit = (int)min((long long)BLOCK, (long long)n - base);

    // ---- stage poses: coalesced linear copy of limit*7 contiguous floats ----
    {
        const float* psrc = poses + base * 7;
        const int tot = limit * 7;
        #pragma unroll
        for (int k = 0; k < 7; ++k) {
            int idx = tid + k * BLOCK;
            if (idx < tot) sp[idx] = psrc[idx];
        }
    }
    __syncthreads();

    if (tid < limit) {
        const long long e = base + tid;

        // edge indices (int32 pair, 8B coalesced)
        const int2 ed = ((const int2*)edges)[e];

        // pose from LDS (stride 7: gcd(7,32)=1 -> <=2 lanes/bank, free)
        const float* p = &sp[tid * 7];
        F3 tp{p[0], p[1], p[2]};
        F4 qp{p[3], p[4], p[5], p[6]};

        // nodes gather (L2-resident: nodes array is 2.8 MB)
        const float* n1p = nodes + (size_t)ed.x * 7;
        const float* n2p = nodes + (size_t)ed.y * 7;
        F3 t1{n1p[0], n1p[1], n1p[2]};
        F4 q1{n1p[3], n1p[4], n1p[5], n1p[6]};
        F3 t2{n2p[0], n2p[1], n2p[2]};
        F4 q2{n2p[3], n2p[4], n2p[5], n2p[6]};

        // inv(pose): qc = conj(qp), ti = -qrot(qc, tp)
        F4 qpc{-qp.x, -qp.y, -qp.z, qp.w};
        F3 tpi = neg3(qrot(qpc, tp));

        // A = inv(pose) * node2
        F3 tA = add3(tpi, qrot(qpc, t2));
        F4 qA = qmul(qpc, q2);

        // inv(node1)
        F4 q1c{-q1.x, -q1.y, -q1.z, q1.w};
        F3 t1i = neg3(qrot(q1c, t1));

        // E = A * inv(node1)
        F3 tE = add3(tA, qrot(qA, t1i));
        F4 qE = qmul(qA, q1c);

        // ---- so3_log ----
        F3 v{qE.x, qE.y, qE.z};
        float w = qE.w;
        float nn = sqrtf(v.x * v.x + v.y * v.y + v.z * v.z);
        float n_safe = (nn > EPS) ? nn : 1.0f;
        float w_safe = (fabsf(w) > EPS) ? w : 1.0f;
        float scale = (nn > EPS) ? (2.0f * atan2f(nn, w) / n_safe)
                                 : (2.0f / w_safe);
        F3 phi{v.x * scale, v.y * scale, v.z * scale};

        // ---- se3_log ----
        float theta2 = phi.x * phi.x + phi.y * phi.y + phi.z * phi.z;
        float theta = sqrtf(theta2);
        bool small = theta < EPS;
        float th = small ? 1.0f : theta;
        float s, cth;
        sincosf(th, &s, &cth);
        float c = small ? (1.0f / 12.0f)
                        : (1.0f / (th * th) - (1.0f + cth) / (2.0f * th * s));
        F3 pxt = cross3(phi, tE);
        F3 ppxt = cross3(phi, pxt);
        F3 tau{tE.x - 0.5f * pxt.x + c * ppxt.x,
               tE.y - 0.5f * pxt.y + c * ppxt.y,
               tE.z - 0.5f * pxt.z + c * ppxt.z};

        float* o = &so[tid * 6];
        o[0] = tau.x; o[1] = tau.y; o[2] = tau.z;
        o[3] = phi.x; o[4] = phi.y; o[5] = phi.z;
    }
    __syncthreads();

    // ---- coalesced linear store of limit*6 contiguous floats ----
    {
        float* odst = out + base * 6;
        const int tot = limit * 6;
        #pragma unroll
        for (int k = 0; k < 6; ++k) {
            int idx = tid + k * BLOCK;
            if (idx < tot) odst[idx] = so[idx];
        }
    }
}

extern "C" void kernel_launch(void* const* d_in, const int* in_sizes, int n_in,
                              void* d_out, int out_size, void* d_ws, size_t ws_size,
                              hipStream_t stream) {
    const int* edges = (const int*)d_in[0];
    const float* poses = (const float*)d_in[1];
    const float* nodes = (const float*)d_in[2];
    float* out = (float*)d_out;

    const int n_edges = in_sizes[0] / 2;  // edges is [n,2]
    const int grid = (n_edges + BLOCK - 1) / BLOCK;

    pose_graph_kernel<<<grid, BLOCK, 0, stream>>>(edges, poses, nodes, out, n_edges);
}

// Round 2
// 220.890 us; speedup vs baseline: 1.0386x; 1.0386x over previous
//
#include <hip/hip_runtime.h>
#include <math.h>

#define BLOCK 256
#define EPS 1e-6f

struct F3 { float x, y, z; };
struct F4 { float x, y, z, w; };

__device__ __forceinline__ F3 cross3(F3 a, F3 b) {
    return F3{a.y * b.z - a.z * b.y,
              a.z * b.x - a.x * b.z,
              a.x * b.y - a.y * b.x};
}
__device__ __forceinline__ F3 add3(F3 a, F3 b) { return F3{a.x + b.x, a.y + b.y, a.z + b.z}; }
__device__ __forceinline__ F3 neg3(F3 a) { return F3{-a.x, -a.y, -a.z}; }

__device__ __forceinline__ F3 qrot(F4 q, F3 v) {
    F3 u{q.x, q.y, q.z};
    F3 t = cross3(u, v);
    t.x *= 2.0f; t.y *= 2.0f; t.z *= 2.0f;
    F3 c = cross3(u, t);
    return F3{v.x + q.w * t.x + c.x,
              v.y + q.w * t.y + c.y,
              v.z + q.w * t.z + c.z};
}
__device__ __forceinline__ F4 qmul(F4 q, F4 r) {
    return F4{
        q.w * r.x + q.x * r.w + q.y * r.z - q.z * r.y,
        q.w * r.y - q.x * r.z + q.y * r.w + q.z * r.x,
        q.w * r.z + q.x * r.y - q.y * r.x + q.z * r.w,
        q.w * r.w - q.x * r.x - q.y * r.y - q.z * r.z};
}

// ---- prologue: nodes [N,7] -> d_ws [N,8] (32B records, 16B-aligned) ----
__global__ void __launch_bounds__(BLOCK) repack_nodes_kernel(
    const float* __restrict__ nodes, float* __restrict__ nodes8, int total7)
{
    int idx = blockIdx.x * BLOCK + threadIdx.x;
    int stride = gridDim.x * BLOCK;
    for (; idx < total7; idx += stride) {
        int node = idx / 7;              // magic-mul div
        int comp = idx - node * 7;
        nodes8[node * 8 + comp] = nodes[idx];
    }
}

__device__ __forceinline__ void compute_edge(
    const float* __restrict__ p,      // pose 7 floats (LDS)
    F3 t1, F4 q1, F3 t2, F4 q2,       // gathered nodes
    float* __restrict__ o)            // 6-float output slot (LDS)
{
    F3 tp{p[0], p[1], p[2]};
    F4 qp{p[3], p[4], p[5], p[6]};

    F4 qpc{-qp.x, -qp.y, -qp.z, qp.w};
    F3 tpi = neg3(qrot(qpc, tp));

    F3 tA = add3(tpi, qrot(qpc, t2));
    F4 qA = qmul(qpc, q2);

    F4 q1c{-q1.x, -q1.y, -q1.z, q1.w};
    F3 t1i = neg3(qrot(q1c, t1));

    F3 tE = add3(tA, qrot(qA, t1i));
    F4 qE = qmul(qA, q1c);

    // so3_log
    F3 v{qE.x, qE.y, qE.z};
    float w = qE.w;
    float nn = sqrtf(v.x * v.x + v.y * v.y + v.z * v.z);
    float n_safe = (nn > EPS) ? nn : 1.0f;
    float w_safe = (fabsf(w) > EPS) ? w : 1.0f;
    float scale = (nn > EPS) ? (2.0f * atan2f(nn, w) / n_safe)
                             : (2.0f / w_safe);
    F3 phi{v.x * scale, v.y * scale, v.z * scale};

    // se3_log
    float theta2 = phi.x * phi.x + phi.y * phi.y + phi.z * phi.z;
    float theta = sqrtf(theta2);
    bool small = theta < EPS;
    float th = small ? 1.0f : theta;
    float s, cth;
    sincosf(th, &s, &cth);
    float c = small ? (1.0f / 12.0f)
                    : (1.0f / (th * th) - (1.0f + cth) / (2.0f * th * s));
    F3 pxt = cross3(phi, tE);
    F3 ppxt = cross3(phi, pxt);
    o[0] = tE.x - 0.5f * pxt.x + c * ppxt.x;
    o[1] = tE.y - 0.5f * pxt.y + c * ppxt.y;
    o[2] = tE.z - 0.5f * pxt.z + c * ppxt.z;
    o[3] = phi.x; o[4] = phi.y; o[5] = phi.z;
}

__global__ void __launch_bounds__(BLOCK) pose_graph_kernel(
    const int* __restrict__ edges,     // [n,2] int32
    const float* __restrict__ poses,   // [n,7]
    const float* __restrict__ nodes8,  // [N_NODES,8] repacked
    float* __restrict__ out,           // [n,6]
    int n)
{
    __shared__ float4 sp4[(BLOCK * 7 + 3) / 4];   // 448 * 16B = 7168 B
    __shared__ float  so[BLOCK * 6];              // 6144 B

    const int tid = threadIdx.x;
    const long long base = (long long)blockIdx.x * BLOCK;
    const int limit = (int)min((long long)BLOCK, (long long)n - base);
    float* sp = (float*)sp4;

    // ---- stage poses (vectorized for full blocks, scalar tail) ----
    if (limit == BLOCK) {
        const float4* psrc = (const float4*)(poses + base * 7);  // 16B-aligned: base*28 % 16 == 0 (base mult of 256)
        sp4[tid] = psrc[tid];
        if (tid < (BLOCK * 7 / 4) - BLOCK)       // 448 - 256 = 192
            sp4[tid + BLOCK] = psrc[tid + BLOCK];
    } else {
        const float* psrc = poses + base * 7;
        const int tot = limit * 7;
        for (int idx = tid; idx < tot; idx += BLOCK) sp[idx] = psrc[idx];
    }
    __syncthreads();

    if (tid < limit) {
        const long long e = base + tid;
        const int2 ed = ((const int2*)edges)[e];

        // vectorized gather: 32B records, two dwordx4 each
        const float4* n1p = (const float4*)(nodes8 + (size_t)ed.x * 8);
        const float4* n2p = (const float4*)(nodes8 + (size_t)ed.y * 8);
        float4 a1 = n1p[0], b1 = n1p[1];
        float4 a2 = n2p[0], b2 = n2p[1];

        F3 t1{a1.x, a1.y, a1.z};
        F4 q1{a1.w, b1.x, b1.y, b1.z};
        F3 t2{a2.x, a2.y, a2.z};
        F4 q2{a2.w, b2.x, b2.y, b2.z};

        compute_edge(&sp[tid * 7], t1, q1, t2, q2, &so[tid * 6]);
    }
    __syncthreads();

    // ---- store output (vectorized for full blocks) ----
    if (limit == BLOCK) {
        float4* odst = (float4*)(out + base * 6);  // base*24 % 16 == 0
        float4* sov = (float4*)so;
        odst[tid] = sov[tid];
        if (tid < (BLOCK * 6 / 4) - BLOCK)         // 384 - 256 = 128
            odst[tid + BLOCK] = sov[tid + BLOCK];
    } else {
        float* odst = out + base * 6;
        const int tot = limit * 6;
        for (int idx = tid; idx < tot; idx += BLOCK) odst[idx] = so[idx];
    }
}

// fallback (ws too small): direct scalar gathers from [N,7] nodes
__global__ void __launch_bounds__(BLOCK) pose_graph_kernel_fallback(
    const int* __restrict__ edges, const float* __restrict__ poses,
    const float* __restrict__ nodes, float* __restrict__ out, int n)
{
    __shared__ float sp[BLOCK * 7];
    __shared__ float so[BLOCK * 6];
    const int tid = threadIdx.x;
    const long long base = (long long)blockIdx.x * BLOCK;
    const int limit = (int)min((long long)BLOCK, (long long)n - base);
    {
        const float* psrc = poses + base * 7;
        const int tot = limit * 7;
        for (int idx = tid; idx < tot; idx += BLOCK) sp[idx] = psrc[idx];
    }
    __syncthreads();
    if (tid < limit) {
        const long long e = base + tid;
        const int2 ed = ((const int2*)edges)[e];
        const float* n1p = nodes + (size_t)ed.x * 7;
        const float* n2p = nodes + (size_t)ed.y * 7;
        F3 t1{n1p[0], n1p[1], n1p[2]};
        F4 q1{n1p[3], n1p[4], n1p[5], n1p[6]};
        F3 t2{n2p[0], n2p[1], n2p[2]};
        F4 q2{n2p[3], n2p[4], n2p[5], n2p[6]};
        compute_edge(&sp[tid * 7], t1, q1, t2, q2, &so[tid * 6]);
    }
    __syncthreads();
    {
        float* odst = out + base * 6;
        const int tot = limit * 6;
        for (int idx = tid; idx < tot; idx += BLOCK) odst[idx] = so[idx];
    }
}

extern "C" void kernel_launch(void* const* d_in, const int* in_sizes, int n_in,
                              void* d_out, int out_size, void* d_ws, size_t ws_size,
                              hipStream_t stream) {
    const int* edges = (const int*)d_in[0];
    const float* poses = (const float*)d_in[1];
    const float* nodes = (const float*)d_in[2];
    float* out = (float*)d_out;

    const int n_edges = in_sizes[0] / 2;
    const int n_nodes = in_sizes[2] / 7;
    const int grid = (n_edges + BLOCK - 1) / BLOCK;

    const size_t ws_needed = (size_t)n_nodes * 8 * sizeof(float);
    if (ws_size >= ws_needed) {
        float* nodes8 = (float*)d_ws;
        const int total7 = n_nodes * 7;
        const int rgrid = (total7 + BLOCK - 1) / BLOCK;
        repack_nodes_kernel<<<rgrid, BLOCK, 0, stream>>>(nodes, nodes8, total7);
        pose_graph_kernel<<<grid, BLOCK, 0, stream>>>(edges, poses, nodes8, out, n_edges);
    } else {
        pose_graph_kernel_fallback<<<grid, BLOCK, 0, stream>>>(edges, poses, nodes, out, n_edges);
    }
}